// Round 2
// baseline (618.595 us; speedup 1.0000x reference)
//
#include <hip/hip_runtime.h>

#define N_NODES 50000
#define N_EDGES 640000
#define F 128
#define DFF 512

// ---------------- CSR build ----------------
__global__ void k_hist(const int* __restrict__ dst, int* __restrict__ cnt) {
    int e = blockIdx.x * 256 + threadIdx.x;
    if (e < N_EDGES) atomicAdd(&cnt[dst[e]], 1);
}

__global__ void k_scan(const int* __restrict__ counts, int* __restrict__ row_ptr, int n) {
    __shared__ int s_ws[16];
    __shared__ int s_run;
    const int t = threadIdx.x;
    const int lane = t & 63;
    const int wid = t >> 6;
    if (t == 0) s_run = 0;
    for (int base = 0; base < n; base += 1024) {
        __syncthreads();
        int run = s_run;
        int x = (base + t < n) ? counts[base + t] : 0;
        int vsc = x;
#pragma unroll
        for (int off = 1; off < 64; off <<= 1) {
            int u = __shfl_up(vsc, off, 64);
            if (lane >= off) vsc += u;
        }
        if (lane == 63) s_ws[wid] = vsc;
        __syncthreads();
        if (t < 64) {
            int wv = (lane < 16) ? s_ws[lane] : 0;
#pragma unroll
            for (int off = 1; off < 16; off <<= 1) {
                int u = __shfl_up(wv, off, 64);
                if (lane >= off) wv += u;
            }
            if (lane < 16) s_ws[lane] = wv;
        }
        __syncthreads();
        int woff = (wid == 0) ? 0 : s_ws[wid - 1];
        int incl = vsc + woff;
        if (base + t < n) row_ptr[base + t] = run + incl - x;
        __syncthreads();
        if (t == 0) s_run = run + s_ws[15];
    }
    __syncthreads();
    if (t == 0) row_ptr[n] = s_run;
}

__global__ void k_fill(const int* __restrict__ src, const int* __restrict__ dst,
                       const int* __restrict__ row_ptr, int* __restrict__ fill,
                       int* __restrict__ csr_src) {
    int e = blockIdx.x * 256 + threadIdx.x;
    if (e < N_EDGES) {
        int d = dst[e];
        int pos = row_ptr[d] + atomicAdd(&fill[d], 1);
        csr_src[pos] = src[e];
    }
}

// ---------------- tiled GEMM, 32 rows x 128 cols per block, K-chunk 64 ----------------
// All operands fp32.
// EPI: 0 = plain store, 1 = +bias, PReLU, 2 = +bias +resid, LayerNorm
template <int EPI>
__global__ __launch_bounds__(256) void k_gemm(
    const float* __restrict__ A, int lda,
    const float* __restrict__ B, int ldb,
    float* __restrict__ C, int ldc,
    int K,
    const float* __restrict__ bias,
    const float* __restrict__ prelu,
    const float* __restrict__ resid,
    const float* __restrict__ g,
    const float* __restrict__ bb)
{
    __shared__ float smem[32 * 64 + 64 * 128];   // 40 KB
    float* sA = smem;            // [32][64]
    float* sB = smem + 32 * 64;  // [64][128]

    const int t = threadIdx.x;
    const int tx = t & 31;   // col group (4 cols)
    const int ty = t >> 5;   // row group (4 rows)
    const int row0 = blockIdx.x * 32;
    const int cb = blockIdx.y * 128;

    float acc[4][4] = {};

    for (int kc = 0; kc < K; kc += 64) {
        // stage A tile (32 x 64)
#pragma unroll
        for (int i = 0; i < 2; ++i) {
            int u = i * 256 + t;       // 512 float4 units
            int r = u >> 4, k4 = (u & 15) * 4;
            float4 val = make_float4(0.f, 0.f, 0.f, 0.f);
            if (row0 + r < N_NODES)
                val = *reinterpret_cast<const float4*>(A + (size_t)(row0 + r) * lda + kc + k4);
            *reinterpret_cast<float4*>(&sA[r * 64 + k4]) = val;
        }
        // stage B tile (64 x 128)
#pragma unroll
        for (int i = 0; i < 8; ++i) {
            int u = i * 256 + t;       // 2048 float4 units
            int kk = u >> 5, c4 = (u & 31) * 4;
            *reinterpret_cast<float4*>(&sB[kk * 128 + c4]) =
                *reinterpret_cast<const float4*>(B + (size_t)(kc + kk) * ldb + cb + c4);
        }
        __syncthreads();
#pragma unroll 16
        for (int kk = 0; kk < 64; ++kk) {
            float a0 = sA[(4 * ty + 0) * 64 + kk];
            float a1 = sA[(4 * ty + 1) * 64 + kk];
            float a2 = sA[(4 * ty + 2) * 64 + kk];
            float a3 = sA[(4 * ty + 3) * 64 + kk];
            float4 b4 = *reinterpret_cast<const float4*>(&sB[kk * 128 + 4 * tx]);
            acc[0][0] += a0 * b4.x; acc[0][1] += a0 * b4.y; acc[0][2] += a0 * b4.z; acc[0][3] += a0 * b4.w;
            acc[1][0] += a1 * b4.x; acc[1][1] += a1 * b4.y; acc[1][2] += a1 * b4.z; acc[1][3] += a1 * b4.w;
            acc[2][0] += a2 * b4.x; acc[2][1] += a2 * b4.y; acc[2][2] += a2 * b4.z; acc[2][3] += a2 * b4.w;
            acc[3][0] += a3 * b4.x; acc[3][1] += a3 * b4.y; acc[3][2] += a3 * b4.z; acc[3][3] += a3 * b4.w;
        }
        __syncthreads();
    }

    if (EPI == 0) {
#pragma unroll
        for (int ri = 0; ri < 4; ++ri) {
            int row = row0 + 4 * ty + ri;
            if (row < N_NODES) {
                float4 o = make_float4(acc[ri][0], acc[ri][1], acc[ri][2], acc[ri][3]);
                *reinterpret_cast<float4*>(&C[(size_t)row * ldc + cb + 4 * tx]) = o;
            }
        }
    } else if (EPI == 1) {
        float bs[4], pr[4];
#pragma unroll
        for (int j = 0; j < 4; ++j) {
            bs[j] = bias[cb + 4 * tx + j];
            pr[j] = prelu[cb + 4 * tx + j];
        }
#pragma unroll
        for (int ri = 0; ri < 4; ++ri) {
            int row = row0 + 4 * ty + ri;
            if (row < N_NODES) {
                float4 o;
                float v0 = acc[ri][0] + bs[0]; o.x = v0 >= 0.f ? v0 : pr[0] * v0;
                float v1 = acc[ri][1] + bs[1]; o.y = v1 >= 0.f ? v1 : pr[1] * v1;
                float v2 = acc[ri][2] + bs[2]; o.z = v2 >= 0.f ? v2 : pr[2] * v2;
                float v3 = acc[ri][3] + bs[3]; o.w = v3 >= 0.f ? v3 : pr[3] * v3;
                *reinterpret_cast<float4*>(&C[(size_t)row * ldc + cb + 4 * tx]) = o;
            }
        }
    } else {
        // +bias +resid, per-row LayerNorm, fp32 store. grid.y==1, tile covers all 128 cols.
        float* sC = smem;             // 32*128 floats, reuses sA/sB (synced above)
        float* s_mu = smem + 4096;
        float* s_rs = smem + 4160;
        float bs[4];
#pragma unroll
        for (int j = 0; j < 4; ++j) bs[j] = bias[cb + 4 * tx + j];
#pragma unroll
        for (int ri = 0; ri < 4; ++ri) {
            int row = row0 + 4 * ty + ri;
#pragma unroll
            for (int j = 0; j < 4; ++j) {
                float vv = acc[ri][j] + bs[j];
                if (row < N_NODES) vv += resid[(size_t)row * 128 + 4 * tx + j];
                sC[(4 * ty + ri) * 128 + 4 * tx + j] = vv;
            }
        }
        __syncthreads();
        {
            int r = t >> 3, part = t & 7;
            float ps = 0.f, pq = 0.f;
#pragma unroll
            for (int i = 0; i < 16; ++i) {
                float xv = sC[r * 128 + part * 16 + i];
                ps += xv; pq += xv * xv;
            }
            ps += __shfl_xor(ps, 4, 8); pq += __shfl_xor(pq, 4, 8);
            ps += __shfl_xor(ps, 2, 8); pq += __shfl_xor(pq, 2, 8);
            ps += __shfl_xor(ps, 1, 8); pq += __shfl_xor(pq, 1, 8);
            if (part == 0) {
                float mu = ps * (1.f / 128.f);
                float var = pq * (1.f / 128.f) - mu * mu;
                s_mu[r] = mu;
                s_rs[r] = rsqrtf(var + 1e-5f);
            }
        }
        __syncthreads();
#pragma unroll
        for (int i = 0; i < 16; ++i) {
            int idx = i * 256 + t;
            int r = idx >> 7, c = idx & 127;
            int row = row0 + r;
            if (row < N_NODES) {
                float xv = sC[idx];
                C[(size_t)row * 128 + c] = (xv - s_mu[r]) * s_rs[r] * g[c] + bb[c];
            }
        }
    }
}

// ---------------- per-node online-softmax aggregation + residual + LN1 ----------------
__global__ __launch_bounds__(128) void k_attn(
    const float* __restrict__ q, const float* __restrict__ k, const float* __restrict__ v,
    const float* __restrict__ feat,
    const int* __restrict__ row_ptr, const int* __restrict__ csr_src,
    const float* __restrict__ g, const float* __restrict__ bb,
    float* __restrict__ rst_ln)
{
    const int n = blockIdx.x;
    const int t = threadIdx.x;          // head = t/16, dim = t%16
    const float scale = 0.08838834764831845f;  // 1/sqrt(128)

    const float qv = q[(size_t)n * 128 + t];
    const int e0 = row_ptr[n], e1 = row_ptr[n + 1];

    float m = -INFINITY, l = 0.f, acc = 0.f;
    for (int e = e0; e < e1; ++e) {
        int sn = csr_src[e];
        float kv = k[(size_t)sn * 128 + t];
        float p = kv * qv;
        p += __shfl_xor(p, 8, 16);
        p += __shfl_xor(p, 4, 16);
        p += __shfl_xor(p, 2, 16);
        p += __shfl_xor(p, 1, 16);
        float s = p * scale;
        float mn = fmaxf(m, s);
        float corr = __expf(m - mn);    // exp(-inf) = 0 on first edge
        float pe = __expf(s - mn);
        float vv = v[(size_t)sn * 128 + t];
        l = l * corr + pe;
        acc = acc * corr + pe * vv;
        m = mn;
    }
    float ft2 = (l > 0.f) ? acc / l : 0.f;  // deg-0 node -> 0 (matches segment_sum)
    float x = ft2 + feat[(size_t)n * 128 + t];

    // LayerNorm over 128 channels (2 waves)
    float sum = x, sq = x * x;
#pragma unroll
    for (int off = 32; off >= 1; off >>= 1) {
        sum += __shfl_xor(sum, off, 64);
        sq += __shfl_xor(sq, off, 64);
    }
    __shared__ float s_sum[2], s_sq[2];
    if ((t & 63) == 0) { s_sum[t >> 6] = sum; s_sq[t >> 6] = sq; }
    __syncthreads();
    float ts = s_sum[0] + s_sum[1], tq = s_sq[0] + s_sq[1];
    float mu = ts * (1.f / 128.f);
    float var = tq * (1.f / 128.f) - mu * mu;
    float rs = rsqrtf(var + 1e-5f);
    rst_ln[(size_t)n * 128 + t] = (x - mu) * rs * g[t] + bb[t];
}

extern "C" void kernel_launch(void* const* d_in, const int* in_sizes, int n_in,
                              void* d_out, int out_size, void* d_ws, size_t ws_size,
                              hipStream_t stream)
{
    const float* feat = (const float*)d_in[0];
    const int* src    = (const int*)d_in[1];
    const int* dst    = (const int*)d_in[2];
    const float* Wq   = (const float*)d_in[3];
    const float* Wk   = (const float*)d_in[4];
    const float* Wv   = (const float*)d_in[5];
    const float* ln_g = (const float*)d_in[6];
    const float* ln_b = (const float*)d_in[7];
    const float* W1   = (const float*)d_in[8];
    const float* b1   = (const float*)d_in[9];
    const float* pa   = (const float*)d_in[10];
    const float* W2   = (const float*)d_in[11];
    const float* b2   = (const float*)d_in[12];

    const size_t NF = (size_t)N_NODES * F;         // 6.4M floats
    float* q   = (float*)d_ws;
    float* kk  = q + NF;
    float* vv  = kk + NF;
    float* h   = q;                                 // h (N x 512) aliases q,k,v region
    float* rst = q + 4 * NF;                        // survives through ffn2
    int* counts  = (int*)(rst + NF);
    int* fill    = counts + N_NODES;
    int* row_ptr = fill + N_NODES;
    int* csr_src = row_ptr + N_NODES + 1;

    hipMemsetAsync(counts, 0, sizeof(int) * 2 * N_NODES, stream);
    k_hist<<<(N_EDGES + 255) / 256, 256, 0, stream>>>(dst, counts);
    k_scan<<<1, 1024, 0, stream>>>(counts, row_ptr, N_NODES);
    k_fill<<<(N_EDGES + 255) / 256, 256, 0, stream>>>(src, dst, row_ptr, fill, csr_src);

    dim3 gq((N_NODES + 31) / 32, 1);
    k_gemm<0><<<gq, 256, 0, stream>>>(feat, F, Wq, F, q,  F, F,
                                      nullptr, nullptr, nullptr, nullptr, nullptr);
    k_gemm<0><<<gq, 256, 0, stream>>>(feat, F, Wk, F, kk, F, F,
                                      nullptr, nullptr, nullptr, nullptr, nullptr);
    k_gemm<0><<<gq, 256, 0, stream>>>(feat, F, Wv, F, vv, F, F,
                                      nullptr, nullptr, nullptr, nullptr, nullptr);

    k_attn<<<N_NODES, 128, 0, stream>>>(q, kk, vv, feat, row_ptr, csr_src, ln_g, ln_b, rst);

    dim3 gf1((N_NODES + 31) / 32, 4);
    k_gemm<1><<<gf1, 256, 0, stream>>>(rst, F, W1, DFF, h, DFF, F,
                                       b1, pa, nullptr, nullptr, nullptr);

    dim3 gf2((N_NODES + 31) / 32, 1);
    k_gemm<2><<<gf2, 256, 0, stream>>>(h, DFF, W2, F, (float*)d_out, F, DFF,
                                       b2, nullptr, rst, ln_g, ln_b);
}

// Round 3
// 429.063 us; speedup vs baseline: 1.4417x; 1.4417x over previous
//
#include <hip/hip_runtime.h>

#define N_NODES 50000
#define N_EDGES 640000
#define F 128
#define DFF 512

using u32 = unsigned int;
using u16 = unsigned short;

typedef __bf16 bf16x8 __attribute__((ext_vector_type(8)));
typedef float f32x4 __attribute__((ext_vector_type(4)));

__device__ __forceinline__ float bf2f(u16 u) {
    return __uint_as_float(((u32)u) << 16);
}
__device__ __forceinline__ u16 f2bf(float f) {
    u32 u = __float_as_uint(f);
    u += 0x7fffu + ((u >> 16) & 1u);   // RNE
    return (u16)(u >> 16);
}
__device__ __forceinline__ u32 pack2(float a, float b) {
    return (u32)f2bf(a) | ((u32)f2bf(b) << 16);
}

// ---------------- CSR build ----------------
__global__ void k_hist(const int* __restrict__ dst, int* __restrict__ cnt) {
    int e = blockIdx.x * 256 + threadIdx.x;
    if (e < N_EDGES) atomicAdd(&cnt[dst[e]], 1);
}

// 1024 threads: each scans a contiguous chunk serially, then one block-scan.
__global__ void k_scan(const int* __restrict__ counts, int* __restrict__ row_ptr, int n) {
    const int t = threadIdx.x;
    const int CH = (n + 1023) / 1024;
    int b0 = t * CH;
    int e0 = b0 + CH; if (e0 > n) e0 = n;
    int s = 0;
    for (int i = b0; i < e0; ++i) s += counts[i];

    __shared__ int ws[16];
    const int lane = t & 63, wid = t >> 6;
    int incl = s;
#pragma unroll
    for (int off = 1; off < 64; off <<= 1) {
        int u = __shfl_up(incl, off, 64);
        if (lane >= off) incl += u;
    }
    if (lane == 63) ws[wid] = incl;
    __syncthreads();
    if (t < 64) {
        int wv = (lane < 16) ? ws[lane] : 0;
#pragma unroll
        for (int off = 1; off < 16; off <<= 1) {
            int u = __shfl_up(wv, off, 64);
            if (lane >= off) wv += u;
        }
        if (lane < 16) ws[lane] = wv;
    }
    __syncthreads();
    int base = incl - s + (wid ? ws[wid - 1] : 0);   // exclusive prefix
    int run = base;
    for (int i = b0; i < e0; ++i) { row_ptr[i] = run; run += counts[i]; }
    if (t == 1023) row_ptr[n] = run;                 // = total = N_EDGES
}

__global__ void k_fill(const int* __restrict__ src, const int* __restrict__ dst,
                       const int* __restrict__ row_ptr, int* __restrict__ fill,
                       int* __restrict__ csr_src) {
    int e = blockIdx.x * 256 + threadIdx.x;
    if (e < N_EDGES) {
        int d = dst[e];
        int pos = row_ptr[d] + atomicAdd(&fill[d], 1);
        csr_src[pos] = src[e];
    }
}

// ---------------- weight prep: WT[n][k] = bf16(W[k][n]) ----------------
__global__ void k_prep(const float* __restrict__ W, u16* __restrict__ WT, int K, int Ncol) {
    int idx = blockIdx.x * 256 + threadIdx.x;
    if (idx < K * Ncol) {
        int n = idx / K, k = idx - n * K;
        WT[idx] = f2bf(W[(size_t)k * Ncol + n]);
    }
}

// ---------------- MFMA GEMM: 128x128 tile, K-chunk 32, bf16 inputs fp32 acc ----------------
// EPI: 0 = bf16 store; 1 = +bias, PReLU, bf16 store; 2 = +bias +resid, LayerNorm, fp32 store
// ABF: A is bf16 (true) or fp32 converted inline (false). BT is [ncols][K] bf16.
template <int EPI, bool ABF>
__global__ __launch_bounds__(256) void k_mm(
    const void* __restrict__ Av, int lda,
    const u16* __restrict__ BT,
    void* __restrict__ Cv, int ldc,
    int K,
    const float* __restrict__ bias,
    const float* __restrict__ prelu,
    const float* __restrict__ resid,
    const float* __restrict__ g,
    const float* __restrict__ bb)
{
    __shared__ u16 sA[128 * 40];   // 32 k + pad to 40 (16B-aligned rows, spread banks)
    __shared__ u16 sB[128 * 40];

    const int t = threadIdx.x;
    const int w = t >> 6;          // wave 0..3 -> rows [w*32, w*32+32)
    const int lane = t & 63;
    const int ln = lane & 15, q4 = lane >> 4;
    const int row0 = blockIdx.x * 128;
    const int cb = blockIdx.y * 128;

    f32x4 acc[2][8];
#pragma unroll
    for (int mt = 0; mt < 2; ++mt)
#pragma unroll
        for (int nt = 0; nt < 8; ++nt)
            acc[mt][nt] = (f32x4){0.f, 0.f, 0.f, 0.f};

    for (int kc = 0; kc < K; kc += 32) {
        // ---- stage A tile (128 rows x 32 k) ----
        if (ABF) {
            const u16* A = (const u16*)Av;
#pragma unroll
            for (int i = 0; i < 2; ++i) {
                int u = i * 256 + t;            // 512 units of 8 bf16
                int r = u >> 2, k8 = (u & 3) * 8;
                int row = row0 + r;
                uint4 val = make_uint4(0, 0, 0, 0);
                if (row < N_NODES)
                    val = *reinterpret_cast<const uint4*>(A + (size_t)row * lda + kc + k8);
                *reinterpret_cast<uint4*>(&sA[r * 40 + k8]) = val;
            }
        } else {
            const float* A = (const float*)Av;
#pragma unroll
            for (int i = 0; i < 4; ++i) {
                int u = i * 256 + t;            // 1024 units of float4
                int r = u >> 3, k4 = (u & 7) * 4;
                int row = row0 + r;
                float4 val = make_float4(0.f, 0.f, 0.f, 0.f);
                if (row < N_NODES)
                    val = *reinterpret_cast<const float4*>(A + (size_t)row * lda + kc + k4);
                uint2 p;
                p.x = pack2(val.x, val.y);
                p.y = pack2(val.z, val.w);
                *reinterpret_cast<uint2*>(&sA[r * 40 + k4]) = p;
            }
        }
        // ---- stage B^T tile (128 n x 32 k), already bf16 ----
#pragma unroll
        for (int i = 0; i < 2; ++i) {
            int u = i * 256 + t;
            int r = u >> 2, k8 = (u & 3) * 8;
            uint4 val = *reinterpret_cast<const uint4*>(BT + (size_t)(cb + r) * K + kc + k8);
            *reinterpret_cast<uint4*>(&sB[r * 40 + k8]) = val;
        }
        __syncthreads();

        bf16x8 aA0 = *reinterpret_cast<const bf16x8*>(&sA[(w * 32 + ln) * 40 + q4 * 8]);
        bf16x8 aA1 = *reinterpret_cast<const bf16x8*>(&sA[(w * 32 + 16 + ln) * 40 + q4 * 8]);
#pragma unroll
        for (int nt = 0; nt < 8; ++nt) {
            bf16x8 bB = *reinterpret_cast<const bf16x8*>(&sB[(nt * 16 + ln) * 40 + q4 * 8]);
            acc[0][nt] = __builtin_amdgcn_mfma_f32_16x16x32_bf16(aA0, bB, acc[0][nt], 0, 0, 0);
            acc[1][nt] = __builtin_amdgcn_mfma_f32_16x16x32_bf16(aA1, bB, acc[1][nt], 0, 0, 0);
        }
        __syncthreads();
    }

    // C frag mapping: row = row0 + w*32 + mt*16 + q4*4 + j ; col = cb + nt*16 + ln
    if (EPI == 0) {
        u16* C = (u16*)Cv;
#pragma unroll
        for (int mt = 0; mt < 2; ++mt)
#pragma unroll
            for (int j = 0; j < 4; ++j) {
                int row = row0 + w * 32 + mt * 16 + q4 * 4 + j;
                if (row < N_NODES) {
#pragma unroll
                    for (int nt = 0; nt < 8; ++nt)
                        C[(size_t)row * ldc + cb + nt * 16 + ln] = f2bf(acc[mt][nt][j]);
                }
            }
    } else if (EPI == 1) {
        u16* C = (u16*)Cv;
        float bs[8], pr[8];
#pragma unroll
        for (int nt = 0; nt < 8; ++nt) {
            int col = cb + nt * 16 + ln;
            bs[nt] = bias[col];
            pr[nt] = prelu[col];
        }
#pragma unroll
        for (int mt = 0; mt < 2; ++mt)
#pragma unroll
            for (int j = 0; j < 4; ++j) {
                int row = row0 + w * 32 + mt * 16 + q4 * 4 + j;
                if (row < N_NODES) {
#pragma unroll
                    for (int nt = 0; nt < 8; ++nt) {
                        float x = acc[mt][nt][j] + bs[nt];
                        x = (x >= 0.f) ? x : pr[nt] * x;
                        C[(size_t)row * ldc + cb + nt * 16 + ln] = f2bf(x);
                    }
                }
            }
    } else {
        // bias + resid + row LayerNorm (block covers all 128 cols), fp32 out
        float* C = (float*)Cv;
        float bs[8], gv[8], bv[8];
#pragma unroll
        for (int nt = 0; nt < 8; ++nt) {
            int col = cb + nt * 16 + ln;
            bs[nt] = bias[col];
            gv[nt] = g[col];
            bv[nt] = bb[col];
        }
#pragma unroll
        for (int mt = 0; mt < 2; ++mt)
#pragma unroll
            for (int j = 0; j < 4; ++j) {
                int row = row0 + w * 32 + mt * 16 + q4 * 4 + j;
                bool ok = row < N_NODES;
                float vals[8];
                float s = 0.f, ss = 0.f;
#pragma unroll
                for (int nt = 0; nt < 8; ++nt) {
                    float x = acc[mt][nt][j] + bs[nt];
                    if (ok) x += resid[(size_t)row * 128 + cb + nt * 16 + ln];
                    vals[nt] = x;
                    s += x; ss += x * x;
                }
                // row lives in the 16 lanes of this quad-group: reduce width 16
                s += __shfl_xor(s, 8, 16); ss += __shfl_xor(ss, 8, 16);
                s += __shfl_xor(s, 4, 16); ss += __shfl_xor(ss, 4, 16);
                s += __shfl_xor(s, 2, 16); ss += __shfl_xor(ss, 2, 16);
                s += __shfl_xor(s, 1, 16); ss += __shfl_xor(ss, 1, 16);
                float mu = s * (1.f / 128.f);
                float var = ss * (1.f / 128.f) - mu * mu;
                float rs = rsqrtf(var + 1e-5f);
                if (ok) {
#pragma unroll
                    for (int nt = 0; nt < 8; ++nt)
                        C[(size_t)row * 128 + cb + nt * 16 + ln] =
                            (vals[nt] - mu) * rs * gv[nt] + bv[nt];
                }
            }
    }
}

// ---------------- per-node online-softmax aggregation + residual + LN1 ----------------
// qkv packed [n][384] bf16: q cols 0-127, k 128-255, v 256-383
__global__ __launch_bounds__(128) void k_attn(
    const u16* __restrict__ qkv, const float* __restrict__ feat,
    const int* __restrict__ row_ptr, const int* __restrict__ csr_src,
    const float* __restrict__ g, const float* __restrict__ bb,
    float* __restrict__ rst)
{
    const int n = blockIdx.x;
    const int t = threadIdx.x;          // head = t/16, dim = t%16
    const float scale = 0.08838834764831845f;  // 1/sqrt(128)

    const float qv = bf2f(qkv[(size_t)n * 384 + t]);
    const int e0 = row_ptr[n], e1 = row_ptr[n + 1];

    float m = -INFINITY, l = 0.f, acc = 0.f;
    int e = e0;
    for (; e + 2 <= e1; e += 2) {
        int s0 = csr_src[e], s1 = csr_src[e + 1];
        float k0 = bf2f(qkv[(size_t)s0 * 384 + 128 + t]);
        float v0 = bf2f(qkv[(size_t)s0 * 384 + 256 + t]);
        float k1 = bf2f(qkv[(size_t)s1 * 384 + 128 + t]);
        float v1 = bf2f(qkv[(size_t)s1 * 384 + 256 + t]);
        float p0 = k0 * qv, p1 = k1 * qv;
        p0 += __shfl_xor(p0, 8, 16); p1 += __shfl_xor(p1, 8, 16);
        p0 += __shfl_xor(p0, 4, 16); p1 += __shfl_xor(p1, 4, 16);
        p0 += __shfl_xor(p0, 2, 16); p1 += __shfl_xor(p1, 2, 16);
        p0 += __shfl_xor(p0, 1, 16); p1 += __shfl_xor(p1, 1, 16);
        float sa = p0 * scale, sb = p1 * scale;
        float mn = fmaxf(m, fmaxf(sa, sb));
        float c = __expf(m - mn);
        float ea = __expf(sa - mn), eb = __expf(sb - mn);
        l = l * c + ea + eb;
        acc = acc * c + ea * v0 + eb * v1;
        m = mn;
    }
    if (e < e1) {
        int s0 = csr_src[e];
        float k0 = bf2f(qkv[(size_t)s0 * 384 + 128 + t]);
        float v0 = bf2f(qkv[(size_t)s0 * 384 + 256 + t]);
        float p0 = k0 * qv;
        p0 += __shfl_xor(p0, 8, 16);
        p0 += __shfl_xor(p0, 4, 16);
        p0 += __shfl_xor(p0, 2, 16);
        p0 += __shfl_xor(p0, 1, 16);
        float sa = p0 * scale;
        float mn = fmaxf(m, sa);
        float c = __expf(m - mn), ea = __expf(sa - mn);
        l = l * c + ea;
        acc = acc * c + ea * v0;
        m = mn;
    }
    float ft2 = (l > 0.f) ? acc / l : 0.f;  // deg-0 node -> 0
    float x = ft2 + feat[(size_t)n * 128 + t];

    // LayerNorm over 128 channels (2 waves)
    float sum = x, sq = x * x;
#pragma unroll
    for (int off = 32; off >= 1; off >>= 1) {
        sum += __shfl_xor(sum, off, 64);
        sq += __shfl_xor(sq, off, 64);
    }
    __shared__ float s_sum[2], s_sq[2];
    if ((t & 63) == 0) { s_sum[t >> 6] = sum; s_sq[t >> 6] = sq; }
    __syncthreads();
    float ts = s_sum[0] + s_sum[1], tq = s_sq[0] + s_sq[1];
    float mu = ts * (1.f / 128.f);
    float var = tq * (1.f / 128.f) - mu * mu;
    float rs = rsqrtf(var + 1e-5f);
    rst[(size_t)n * 128 + t] = (x - mu) * rs * g[t] + bb[t];
}

extern "C" void kernel_launch(void* const* d_in, const int* in_sizes, int n_in,
                              void* d_out, int out_size, void* d_ws, size_t ws_size,
                              hipStream_t stream)
{
    const float* feat = (const float*)d_in[0];
    const int* src    = (const int*)d_in[1];
    const int* dst    = (const int*)d_in[2];
    const float* Wq   = (const float*)d_in[3];
    const float* Wk   = (const float*)d_in[4];
    const float* Wv   = (const float*)d_in[5];
    const float* ln_g = (const float*)d_in[6];
    const float* ln_b = (const float*)d_in[7];
    const float* W1   = (const float*)d_in[8];
    const float* b1   = (const float*)d_in[9];
    const float* pa   = (const float*)d_in[10];
    const float* W2   = (const float*)d_in[11];
    const float* b2   = (const float*)d_in[12];

    // workspace layout (bf16 regions first, all 16B aligned)
    u16* qkv   = (u16*)d_ws;                          // 50000*384
    u16* h     = qkv + (size_t)N_NODES * 384;         // 50000*512
    u16* BqkvT = h + (size_t)N_NODES * 512;           // 384*128
    u16* W1T   = BqkvT + 384 * 128;                   // 512*128
    u16* W2T   = W1T + 512 * 128;                     // 128*512
    float* rst = (float*)(W2T + 128 * 512);           // 50000*128 fp32
    int* counts  = (int*)(rst + (size_t)N_NODES * 128);
    int* fill    = counts + N_NODES;
    int* row_ptr = fill + N_NODES;
    int* csr_src = row_ptr + N_NODES + 1;

    hipMemsetAsync(counts, 0, sizeof(int) * 2 * N_NODES, stream);
    k_hist<<<(N_EDGES + 255) / 256, 256, 0, stream>>>(dst, counts);
    k_scan<<<1, 1024, 0, stream>>>(counts, row_ptr, N_NODES);
    k_fill<<<(N_EDGES + 255) / 256, 256, 0, stream>>>(src, dst, row_ptr, fill, csr_src);

    // weight prep (bf16, transposed)
    k_prep<<<(128 * 128 + 255) / 256, 256, 0, stream>>>(Wq, BqkvT, 128, 128);
    k_prep<<<(128 * 128 + 255) / 256, 256, 0, stream>>>(Wk, BqkvT + 128 * 128, 128, 128);
    k_prep<<<(128 * 128 + 255) / 256, 256, 0, stream>>>(Wv, BqkvT + 2 * 128 * 128, 128, 128);
    k_prep<<<(128 * 512 + 255) / 256, 256, 0, stream>>>(W1, W1T, 128, 512);
    k_prep<<<(512 * 128 + 255) / 256, 256, 0, stream>>>(W2, W2T, 512, 128);

    const int MBK = (N_NODES + 127) / 128;   // 391

    dim3 gqkv(MBK, 3);
    k_mm<0, false><<<gqkv, 256, 0, stream>>>(feat, 128, BqkvT, qkv, 384, 128,
                                             nullptr, nullptr, nullptr, nullptr, nullptr);

    k_attn<<<N_NODES, 128, 0, stream>>>(qkv, feat, row_ptr, csr_src, ln_g, ln_b, rst);

    dim3 gf1(MBK, 4);
    k_mm<1, false><<<gf1, 256, 0, stream>>>(rst, 128, W1T, h, 512, 128,
                                            b1, pa, nullptr, nullptr, nullptr);

    dim3 gf2(MBK, 1);
    k_mm<2, true><<<gf2, 256, 0, stream>>>(h, 512, W2T, d_out, 128, 512,
                                           b2, nullptr, rst, ln_g, ln_b);
}

// Round 4
// 388.966 us; speedup vs baseline: 1.5904x; 1.1031x over previous
//
#include <hip/hip_runtime.h>

#define N_NODES 50000
#define N_EDGES 640000
#define F 128
#define DFF 512

using u32 = unsigned int;
using u16 = unsigned short;

typedef __bf16 bf16x8 __attribute__((ext_vector_type(8)));
typedef float f32x4 __attribute__((ext_vector_type(4)));

__device__ __forceinline__ float bf2f(u16 u) {
    return __uint_as_float(((u32)u) << 16);
}
__device__ __forceinline__ float blo(u32 p) { return __uint_as_float(p << 16); }
__device__ __forceinline__ float bhi(u32 p) { return __uint_as_float(p & 0xffff0000u); }
__device__ __forceinline__ u16 f2bf(float f) {
    u32 u = __float_as_uint(f);
    u += 0x7fffu + ((u >> 16) & 1u);   // RNE
    return (u16)(u >> 16);
}
__device__ __forceinline__ u32 pack2(float a, float b) {
    return (u32)f2bf(a) | ((u32)f2bf(b) << 16);
}

// ---------------- CSR build ----------------
__global__ void k_hist(const int* __restrict__ dst, int* __restrict__ cnt) {
    int e = blockIdx.x * 256 + threadIdx.x;
    if (e < N_EDGES) atomicAdd(&cnt[dst[e]], 1);
}

__global__ void k_scan(const int* __restrict__ counts, int* __restrict__ row_ptr, int n) {
    const int t = threadIdx.x;
    const int CH = (n + 1023) / 1024;
    int b0 = t * CH;
    int e0 = b0 + CH; if (e0 > n) e0 = n;
    int s = 0;
    for (int i = b0; i < e0; ++i) s += counts[i];

    __shared__ int ws[16];
    const int lane = t & 63, wid = t >> 6;
    int incl = s;
#pragma unroll
    for (int off = 1; off < 64; off <<= 1) {
        int u = __shfl_up(incl, off, 64);
        if (lane >= off) incl += u;
    }
    if (lane == 63) ws[wid] = incl;
    __syncthreads();
    if (t < 64) {
        int wv = (lane < 16) ? ws[lane] : 0;
#pragma unroll
        for (int off = 1; off < 16; off <<= 1) {
            int u = __shfl_up(wv, off, 64);
            if (lane >= off) wv += u;
        }
        if (lane < 16) ws[lane] = wv;
    }
    __syncthreads();
    int base = incl - s + (wid ? ws[wid - 1] : 0);   // exclusive prefix
    int run = base;
    for (int i = b0; i < e0; ++i) { row_ptr[i] = run; run += counts[i]; }
    if (t == 1023) row_ptr[n] = run;
}

__global__ void k_fill(const int* __restrict__ src, const int* __restrict__ dst,
                       const int* __restrict__ row_ptr, int* __restrict__ fill,
                       int* __restrict__ csr_src) {
    int e = blockIdx.x * 256 + threadIdx.x;
    if (e < N_EDGES) {
        int d = dst[e];
        int pos = row_ptr[d] + atomicAdd(&fill[d], 1);
        csr_src[pos] = src[e];
    }
}

// ---------------- weight prep: all 5 weights -> bf16 transposed, one kernel ----------------
// layout in WT: [Wq^T 128x128][Wk^T][Wv^T][W1^T 512x128][W2^T 128x512]
__global__ void k_prepw(const float* __restrict__ Wq, const float* __restrict__ Wk,
                        const float* __restrict__ Wv, const float* __restrict__ W1,
                        const float* __restrict__ W2, u16* __restrict__ WT) {
    int idx = blockIdx.x * 256 + threadIdx.x;
    if (idx >= 180224) return;
    if (idx < 49152) {
        int mi = idx >> 14;                 // 0,1,2
        int local = idx & 16383;
        const float* W = (mi == 0) ? Wq : ((mi == 1) ? Wk : Wv);
        int n = local >> 7, k = local & 127;
        WT[idx] = f2bf(W[(size_t)k * 128 + n]);
    } else if (idx < 114688) {
        int local = idx - 49152;
        int n = local >> 7, k = local & 127;
        WT[idx] = f2bf(W1[(size_t)k * 512 + n]);
    } else {
        int local = idx - 114688;
        int n = local >> 9, k = local & 511;
        WT[idx] = f2bf(W2[(size_t)k * 128 + n]);
    }
}

// ---------------- feat fp32 -> bf16 ----------------
__global__ void k_prepA(const float* __restrict__ feat, u16* __restrict__ featb) {
    int idx = blockIdx.x * 256 + threadIdx.x;      // float4 units
    if (idx < N_NODES * F / 4) {
        float4 v = reinterpret_cast<const float4*>(feat)[idx];
        uint2 p;
        p.x = pack2(v.x, v.y);
        p.y = pack2(v.z, v.w);
        reinterpret_cast<uint2*>(featb)[idx] = p;
    }
}

// ---------------- MFMA GEMM: 128x128 tile, K-chunk 64, reg-prefetch, bf16 A/B ----------------
// EPI: 0 = bf16 store; 1 = +bias, PReLU, bf16 store; 2 = +bias +resid(bf16), LayerNorm, fp32
template <int EPI>
__global__ __launch_bounds__(256) void k_mm(
    const u16* __restrict__ A, int lda,
    const u16* __restrict__ BT,
    void* __restrict__ Cv, int ldc,
    int K,
    const float* __restrict__ bias,
    const float* __restrict__ prelu,
    const u16* __restrict__ resid,
    const float* __restrict__ g,
    const float* __restrict__ bb)
{
    __shared__ u16 sA[128 * 72];   // 64 k + pad 8 (16B-aligned rows)
    __shared__ u16 sB[128 * 72];

    const int t = threadIdx.x;
    const int w = t >> 6;
    const int lane = t & 63;
    const int ln = lane & 15, q4 = lane >> 4;
    const int row0 = blockIdx.x * 128;
    const int cb = blockIdx.y * 128;

    f32x4 acc[2][8];
#pragma unroll
    for (int mt = 0; mt < 2; ++mt)
#pragma unroll
        for (int nt = 0; nt < 8; ++nt)
            acc[mt][nt] = (f32x4){0.f, 0.f, 0.f, 0.f};

    uint4 pa[4], pb[4];
    // chunk staging: 1024 uint4 units, unit u -> r = u>>3, k8 = (u&7)*8
#define LOAD_A(kc)                                                             \
    {                                                                          \
        _Pragma("unroll") for (int i = 0; i < 4; ++i) {                        \
            int u = i * 256 + t, r = u >> 3, k8 = (u & 7) * 8;                 \
            int row = row0 + r;                                                \
            uint4 val = make_uint4(0, 0, 0, 0);                                \
            if (row < N_NODES)                                                 \
                val = *reinterpret_cast<const uint4*>(A + (size_t)row * lda + (kc) + k8); \
            pa[i] = val;                                                       \
        }                                                                      \
    }
#define LOAD_B(kc)                                                             \
    {                                                                          \
        _Pragma("unroll") for (int i = 0; i < 4; ++i) {                        \
            int u = i * 256 + t, r = u >> 3, k8 = (u & 7) * 8;                 \
            pb[i] = *reinterpret_cast<const uint4*>(BT + (size_t)(cb + r) * K + (kc) + k8); \
        }                                                                      \
    }

    LOAD_A(0);
    LOAD_B(0);

    for (int kc = 0; kc < K; kc += 64) {
#pragma unroll
        for (int i = 0; i < 4; ++i) {
            int u = i * 256 + t, r = u >> 3, k8 = (u & 7) * 8;
            *reinterpret_cast<uint4*>(&sA[r * 72 + k8]) = pa[i];
            *reinterpret_cast<uint4*>(&sB[r * 72 + k8]) = pb[i];
        }
        __syncthreads();
        if (kc + 64 < K) {
            LOAD_A(kc + 64);
            LOAD_B(kc + 64);
        }
#pragma unroll
        for (int ks = 0; ks < 2; ++ks) {
            bf16x8 a0 = *reinterpret_cast<const bf16x8*>(&sA[(w * 32 + ln) * 72 + ks * 32 + q4 * 8]);
            bf16x8 a1 = *reinterpret_cast<const bf16x8*>(&sA[(w * 32 + 16 + ln) * 72 + ks * 32 + q4 * 8]);
#pragma unroll
            for (int nt = 0; nt < 8; ++nt) {
                bf16x8 b = *reinterpret_cast<const bf16x8*>(&sB[(nt * 16 + ln) * 72 + ks * 32 + q4 * 8]);
                acc[0][nt] = __builtin_amdgcn_mfma_f32_16x16x32_bf16(a0, b, acc[0][nt], 0, 0, 0);
                acc[1][nt] = __builtin_amdgcn_mfma_f32_16x16x32_bf16(a1, b, acc[1][nt], 0, 0, 0);
            }
        }
        __syncthreads();
    }
#undef LOAD_A
#undef LOAD_B

    // C frag: row = row0 + w*32 + mt*16 + q4*4 + j ; col = cb + nt*16 + ln
    if (EPI == 0) {
        u16* C = (u16*)Cv;
#pragma unroll
        for (int mt = 0; mt < 2; ++mt)
#pragma unroll
            for (int j = 0; j < 4; ++j) {
                int row = row0 + w * 32 + mt * 16 + q4 * 4 + j;
                if (row < N_NODES) {
#pragma unroll
                    for (int nt = 0; nt < 8; ++nt)
                        C[(size_t)row * ldc + cb + nt * 16 + ln] = f2bf(acc[mt][nt][j]);
                }
            }
    } else if (EPI == 1) {
        u16* C = (u16*)Cv;
        float bs[8], pr[8];
#pragma unroll
        for (int nt = 0; nt < 8; ++nt) {
            int col = cb + nt * 16 + ln;
            bs[nt] = bias[col];
            pr[nt] = prelu[col];
        }
#pragma unroll
        for (int mt = 0; mt < 2; ++mt)
#pragma unroll
            for (int j = 0; j < 4; ++j) {
                int row = row0 + w * 32 + mt * 16 + q4 * 4 + j;
                if (row < N_NODES) {
#pragma unroll
                    for (int nt = 0; nt < 8; ++nt) {
                        float x = acc[mt][nt][j] + bs[nt];
                        x = (x >= 0.f) ? x : pr[nt] * x;
                        C[(size_t)row * ldc + cb + nt * 16 + ln] = f2bf(x);
                    }
                }
            }
    } else {
        // bias + resid(bf16) + row LayerNorm, fp32 out. Block covers all 128 cols.
        float* C = (float*)Cv;
        float bs[8], gv[8], bv[8];
#pragma unroll
        for (int nt = 0; nt < 8; ++nt) {
            int col = cb + nt * 16 + ln;
            bs[nt] = bias[col];
            gv[nt] = g[col];
            bv[nt] = bb[col];
        }
#pragma unroll
        for (int mt = 0; mt < 2; ++mt)
#pragma unroll
            for (int j = 0; j < 4; ++j) {
                int row = row0 + w * 32 + mt * 16 + q4 * 4 + j;
                bool ok = row < N_NODES;
                float vals[8];
                float s = 0.f, ss = 0.f;
#pragma unroll
                for (int nt = 0; nt < 8; ++nt) {
                    float x = acc[mt][nt][j] + bs[nt];
                    if (ok) x += bf2f(resid[(size_t)row * 128 + cb + nt * 16 + ln]);
                    vals[nt] = x;
                    s += x; ss += x * x;
                }
                s += __shfl_xor(s, 8, 16); ss += __shfl_xor(ss, 8, 16);
                s += __shfl_xor(s, 4, 16); ss += __shfl_xor(ss, 4, 16);
                s += __shfl_xor(s, 2, 16); ss += __shfl_xor(ss, 2, 16);
                s += __shfl_xor(s, 1, 16); ss += __shfl_xor(ss, 1, 16);
                float mu = s * (1.f / 128.f);
                float var = ss * (1.f / 128.f) - mu * mu;
                float rs = rsqrtf(var + 1e-5f);
                if (ok) {
#pragma unroll
                    for (int nt = 0; nt < 8; ++nt)
                        C[(size_t)row * 128 + cb + nt * 16 + ln] =
                            (vals[nt] - mu) * rs * gv[nt] + bv[nt];
                }
            }
    }
}

// ---------------- attention: 1 wave per node, 2 dims per lane, unroll-4 ----------------
// qkv packed [n][384] bf16: q 0-127, k 128-255, v 256-383
__global__ __launch_bounds__(256) void k_attn(
    const u16* __restrict__ qkv, const float* __restrict__ feat,
    const int* __restrict__ row_ptr, const int* __restrict__ csr_src,
    const float* __restrict__ g, const float* __restrict__ bb,
    u16* __restrict__ rstb)
{
    const int w = threadIdx.x >> 6;
    const int lane = threadIdx.x & 63;
    const int n = blockIdx.x * 4 + w;
    if (n >= N_NODES) return;
    const int c2 = lane * 2;                 // dims c2, c2+1 (same head: head = lane>>3)
    const float scale = 0.08838834764831845f;  // 1/sqrt(128)

    const u32 qp = *reinterpret_cast<const u32*>(qkv + (size_t)n * 384 + c2);
    const float q0 = blo(qp), q1 = bhi(qp);
    const int e0 = row_ptr[n], e1 = row_ptr[n + 1];

    float m = -INFINITY, l = 0.f, a0 = 0.f, a1 = 0.f;
    int e = e0;
    for (; e + 4 <= e1; e += 4) {
        int s0 = csr_src[e], s1 = csr_src[e + 1], s2 = csr_src[e + 2], s3 = csr_src[e + 3];
        u32 kp0 = *reinterpret_cast<const u32*>(qkv + (size_t)s0 * 384 + 128 + c2);
        u32 kp1 = *reinterpret_cast<const u32*>(qkv + (size_t)s1 * 384 + 128 + c2);
        u32 kp2 = *reinterpret_cast<const u32*>(qkv + (size_t)s2 * 384 + 128 + c2);
        u32 kp3 = *reinterpret_cast<const u32*>(qkv + (size_t)s3 * 384 + 128 + c2);
        u32 vp0 = *reinterpret_cast<const u32*>(qkv + (size_t)s0 * 384 + 256 + c2);
        u32 vp1 = *reinterpret_cast<const u32*>(qkv + (size_t)s1 * 384 + 256 + c2);
        u32 vp2 = *reinterpret_cast<const u32*>(qkv + (size_t)s2 * 384 + 256 + c2);
        u32 vp3 = *reinterpret_cast<const u32*>(qkv + (size_t)s3 * 384 + 256 + c2);
        float p0 = blo(kp0) * q0 + bhi(kp0) * q1;
        float p1 = blo(kp1) * q0 + bhi(kp1) * q1;
        float p2 = blo(kp2) * q0 + bhi(kp2) * q1;
        float p3 = blo(kp3) * q0 + bhi(kp3) * q1;
        p0 += __shfl_xor(p0, 4, 8); p1 += __shfl_xor(p1, 4, 8);
        p2 += __shfl_xor(p2, 4, 8); p3 += __shfl_xor(p3, 4, 8);
        p0 += __shfl_xor(p0, 2, 8); p1 += __shfl_xor(p1, 2, 8);
        p2 += __shfl_xor(p2, 2, 8); p3 += __shfl_xor(p3, 2, 8);
        p0 += __shfl_xor(p0, 1, 8); p1 += __shfl_xor(p1, 1, 8);
        p2 += __shfl_xor(p2, 1, 8); p3 += __shfl_xor(p3, 1, 8);
        float sa = p0 * scale, sb = p1 * scale, sc = p2 * scale, sd = p3 * scale;
        float mn = fmaxf(fmaxf(m, fmaxf(sa, sb)), fmaxf(sc, sd));
        float c = __expf(m - mn);
        float ea = __expf(sa - mn), eb = __expf(sb - mn);
        float ec = __expf(sc - mn), ed = __expf(sd - mn);
        l = l * c + ((ea + eb) + (ec + ed));
        a0 = a0 * c + ea * blo(vp0) + eb * blo(vp1) + ec * blo(vp2) + ed * blo(vp3);
        a1 = a1 * c + ea * bhi(vp0) + eb * bhi(vp1) + ec * bhi(vp2) + ed * bhi(vp3);
        m = mn;
    }
    for (; e < e1; ++e) {
        int s0 = csr_src[e];
        u32 kp0 = *reinterpret_cast<const u32*>(qkv + (size_t)s0 * 384 + 128 + c2);
        u32 vp0 = *reinterpret_cast<const u32*>(qkv + (size_t)s0 * 384 + 256 + c2);
        float p0 = blo(kp0) * q0 + bhi(kp0) * q1;
        p0 += __shfl_xor(p0, 4, 8);
        p0 += __shfl_xor(p0, 2, 8);
        p0 += __shfl_xor(p0, 1, 8);
        float sa = p0 * scale;
        float mn = fmaxf(m, sa);
        float c = __expf(m - mn), ea = __expf(sa - mn);
        l = l * c + ea;
        a0 = a0 * c + ea * blo(vp0);
        a1 = a1 * c + ea * bhi(vp0);
        m = mn;
    }
    float inv = (l > 0.f) ? 1.f / l : 0.f;   // deg-0 node -> 0
    const float2 fr = *reinterpret_cast<const float2*>(feat + (size_t)n * 128 + c2);
    float x0 = a0 * inv + fr.x;
    float x1 = a1 * inv + fr.y;

    // LayerNorm over 128 channels: full-wave shuffle reduce
    float sum = x0 + x1, sq = x0 * x0 + x1 * x1;
#pragma unroll
    for (int off = 32; off >= 1; off >>= 1) {
        sum += __shfl_xor(sum, off, 64);
        sq += __shfl_xor(sq, off, 64);
    }
    float mu = sum * (1.f / 128.f);
    float var = sq * (1.f / 128.f) - mu * mu;
    float rs = rsqrtf(var + 1e-5f);
    float y0 = (x0 - mu) * rs * g[c2] + bb[c2];
    float y1 = (x1 - mu) * rs * g[c2 + 1] + bb[c2 + 1];
    reinterpret_cast<u32*>(rstb)[(size_t)n * 64 + lane] = pack2(y0, y1);
}

extern "C" void kernel_launch(void* const* d_in, const int* in_sizes, int n_in,
                              void* d_out, int out_size, void* d_ws, size_t ws_size,
                              hipStream_t stream)
{
    const float* feat = (const float*)d_in[0];
    const int* src    = (const int*)d_in[1];
    const int* dst    = (const int*)d_in[2];
    const float* Wq   = (const float*)d_in[3];
    const float* Wk   = (const float*)d_in[4];
    const float* Wv   = (const float*)d_in[5];
    const float* ln_g = (const float*)d_in[6];
    const float* ln_b = (const float*)d_in[7];
    const float* W1   = (const float*)d_in[8];
    const float* b1   = (const float*)d_in[9];
    const float* pa   = (const float*)d_in[10];
    const float* W2   = (const float*)d_in[11];
    const float* b2   = (const float*)d_in[12];

    // workspace layout (~106 MB)
    u16* qkv   = (u16*)d_ws;                           // 50000*384
    u16* h     = qkv + (size_t)N_NODES * 384;          // 50000*512 (featb aliases front)
    u16* featb = h;                                    // 50000*128, dead before h written
    u16* rstb  = h + (size_t)N_NODES * 512;            // 50000*128
    u16* WT    = rstb + (size_t)N_NODES * 128;         // 180224
    u16* BqkvT = WT;
    u16* W1T   = WT + 49152;
    u16* W2T   = WT + 114688;
    int* counts  = (int*)(WT + 180224);
    int* fill    = counts + N_NODES;
    int* row_ptr = fill + N_NODES;
    int* csr_src = row_ptr + N_NODES + 1;

    // prep
    k_prepw<<<(180224 + 255) / 256, 256, 0, stream>>>(Wq, Wk, Wv, W1, W2, WT);
    k_prepA<<<(N_NODES * F / 4 + 255) / 256, 256, 0, stream>>>(feat, featb);

    // CSR
    hipMemsetAsync(counts, 0, sizeof(int) * 2 * N_NODES, stream);
    k_hist<<<(N_EDGES + 255) / 256, 256, 0, stream>>>(dst, counts);
    k_scan<<<1, 1024, 0, stream>>>(counts, row_ptr, N_NODES);
    k_fill<<<(N_EDGES + 255) / 256, 256, 0, stream>>>(src, dst, row_ptr, fill, csr_src);

    const int MBK = (N_NODES + 127) / 128;   // 391

    dim3 gqkv(MBK, 3);
    k_mm<0><<<gqkv, 256, 0, stream>>>(featb, 128, BqkvT, qkv, 384, 128,
                                      nullptr, nullptr, nullptr, nullptr, nullptr);

    k_attn<<<(N_NODES + 3) / 4, 256, 0, stream>>>(qkv, feat, row_ptr, csr_src, ln_g, ln_b, rstb);

    dim3 gf1(MBK, 4);
    k_mm<1><<<gf1, 256, 0, stream>>>(rstb, 128, W1T, h, 512, 128,
                                     b1, pa, nullptr, nullptr, nullptr);

    dim3 gf2(MBK, 1);
    k_mm<2><<<gf2, 256, 0, stream>>>(h, 512, W2T, d_out, 128, 512,
                                     b2, nullptr, rstb, ln_g, ln_b);
}

// Round 5
// 320.074 us; speedup vs baseline: 1.9327x; 1.2152x over previous
//
#include <hip/hip_runtime.h>

#define N_NODES 50000
#define N_EDGES 640000
#define F 128
#define DFF 512
#define NB 196   // ceil(N_NODES/256)

using u32 = unsigned int;
using u16 = unsigned short;

typedef __bf16 bf16x8 __attribute__((ext_vector_type(8)));
typedef float f32x4 __attribute__((ext_vector_type(4)));

__device__ __forceinline__ float bf2f(u16 u) {
    return __uint_as_float(((u32)u) << 16);
}
__device__ __forceinline__ float blo(u32 p) { return __uint_as_float(p << 16); }
__device__ __forceinline__ float bhi(u32 p) { return __uint_as_float(p & 0xffff0000u); }
__device__ __forceinline__ u16 f2bf(float f) {
    u32 u = __float_as_uint(f);
    u += 0x7fffu + ((u >> 16) & 1u);   // RNE
    return (u16)(u >> 16);
}
__device__ __forceinline__ u32 pack2(float a, float b) {
    return (u32)f2bf(a) | ((u32)f2bf(b) << 16);
}

// ---------------- CSR build ----------------
__global__ void k_hist(const int* __restrict__ dst, int* __restrict__ cnt) {
    int e = blockIdx.x * 256 + threadIdx.x;
    if (e < N_EDGES) atomicAdd(&cnt[dst[e]], 1);
}

// per-block sums of counts
__global__ void k_bsum(const int* __restrict__ counts, int* __restrict__ bsum) {
    int i = blockIdx.x * 256 + threadIdx.x;
    int v = (i < N_NODES) ? counts[i] : 0;
#pragma unroll
    for (int off = 32; off >= 1; off >>= 1) v += __shfl_xor(v, off, 64);
    __shared__ int ws[4];
    int lane = threadIdx.x & 63, wid = threadIdx.x >> 6;
    if (lane == 0) ws[wid] = v;
    __syncthreads();
    if (threadIdx.x == 0) bsum[blockIdx.x] = ws[0] + ws[1] + ws[2] + ws[3];
}

// exclusive scan of NB block sums (single block, 256 threads)
__global__ void k_bscan(const int* __restrict__ bsum, int* __restrict__ boff) {
    int t = threadIdx.x;
    int v = (t < NB) ? bsum[t] : 0;
    int lane = t & 63, wid = t >> 6;
    int incl = v;
#pragma unroll
    for (int off = 1; off < 64; off <<= 1) {
        int u = __shfl_up(incl, off, 64);
        if (lane >= off) incl += u;
    }
    __shared__ int ws[4];
    if (lane == 63) ws[wid] = incl;
    __syncthreads();
    int wo = 0;
#pragma unroll
    for (int j = 0; j < 4; ++j) if (j < wid) wo += ws[j];
    if (t < NB) boff[t] = wo + incl - v;
}

// in-block exclusive scan + block offset -> row_ptr
__global__ void k_bfill(const int* __restrict__ counts, const int* __restrict__ boff,
                        int* __restrict__ row_ptr) {
    int b = blockIdx.x, t = threadIdx.x;
    int i = b * 256 + t;
    int v = (i < N_NODES) ? counts[i] : 0;
    int lane = t & 63, wid = t >> 6;
    int incl = v;
#pragma unroll
    for (int off = 1; off < 64; off <<= 1) {
        int u = __shfl_up(incl, off, 64);
        if (lane >= off) incl += u;
    }
    __shared__ int ws[4];
    if (lane == 63) ws[wid] = incl;
    __syncthreads();
    int wo = 0;
#pragma unroll
    for (int j = 0; j < 4; ++j) if (j < wid) wo += ws[j];
    if (i < N_NODES) row_ptr[i] = boff[b] + wo + incl - v;
    if (i == 0) row_ptr[N_NODES] = N_EDGES;   // every dst is in [0, N)
}

__global__ void k_fill(const int* __restrict__ src, const int* __restrict__ dst,
                       const int* __restrict__ row_ptr, int* __restrict__ fill,
                       int* __restrict__ csr_src) {
    int e = blockIdx.x * 256 + threadIdx.x;
    if (e < N_EDGES) {
        int d = dst[e];
        int pos = row_ptr[d] + atomicAdd(&fill[d], 1);
        csr_src[pos] = src[e];
    }
}

// ---------------- weight prep: all 5 weights -> bf16 transposed, one kernel ----------------
// layout in WT: [Wq^T 128x128][Wk^T][Wv^T][W1^T 512x128][W2^T 128x512]
__global__ void k_prepw(const float* __restrict__ Wq, const float* __restrict__ Wk,
                        const float* __restrict__ Wv, const float* __restrict__ W1,
                        const float* __restrict__ W2, u16* __restrict__ WT) {
    int idx = blockIdx.x * 256 + threadIdx.x;
    if (idx >= 180224) return;
    if (idx < 49152) {
        int mi = idx >> 14;                 // 0,1,2
        int local = idx & 16383;
        const float* W = (mi == 0) ? Wq : ((mi == 1) ? Wk : Wv);
        int n = local >> 7, k = local & 127;
        WT[idx] = f2bf(W[(size_t)k * 128 + n]);
    } else if (idx < 114688) {
        int local = idx - 49152;
        int n = local >> 7, k = local & 127;
        WT[idx] = f2bf(W1[(size_t)k * 512 + n]);
    } else {
        int local = idx - 114688;
        int n = local >> 9, k = local & 511;
        WT[idx] = f2bf(W2[(size_t)k * 128 + n]);
    }
}

// ---------------- feat fp32 -> bf16 ----------------
__global__ void k_prepA(const float* __restrict__ feat, u16* __restrict__ featb) {
    int idx = blockIdx.x * 256 + threadIdx.x;      // float4 units
    if (idx < N_NODES * F / 4) {
        float4 v = reinterpret_cast<const float4*>(feat)[idx];
        uint2 p;
        p.x = pack2(v.x, v.y);
        p.y = pack2(v.z, v.w);
        reinterpret_cast<uint2*>(featb)[idx] = p;
    }
}

// ---------------- MFMA GEMM: 128x128 tile, K-chunk 64, reg-prefetch, bf16 A/B ----------------
// EPI: 0 = bf16 store; 1 = +bias, PReLU, bf16 store; 2 = +bias +resid(bf16), LayerNorm, fp32
template <int EPI>
__global__ __launch_bounds__(256) void k_mm(
    const u16* __restrict__ A, int lda,
    const u16* __restrict__ BT,
    void* __restrict__ Cv, int ldc,
    int K,
    const float* __restrict__ bias,
    const float* __restrict__ prelu,
    const u16* __restrict__ resid,
    const float* __restrict__ g,
    const float* __restrict__ bb)
{
    __shared__ u16 sA[128 * 72];   // 64 k + pad 8 (16B-aligned rows)
    __shared__ u16 sB[128 * 72];

    const int t = threadIdx.x;
    const int w = t >> 6;
    const int lane = t & 63;
    const int ln = lane & 15, q4 = lane >> 4;
    const int row0 = blockIdx.x * 128;
    const int cb = blockIdx.y * 128;

    f32x4 acc[2][8];
#pragma unroll
    for (int mt = 0; mt < 2; ++mt)
#pragma unroll
        for (int nt = 0; nt < 8; ++nt)
            acc[mt][nt] = (f32x4){0.f, 0.f, 0.f, 0.f};

    uint4 pa[4], pb[4];
#define LOAD_A(kc)                                                             \
    {                                                                          \
        _Pragma("unroll") for (int i = 0; i < 4; ++i) {                        \
            int u = i * 256 + t, r = u >> 3, k8 = (u & 7) * 8;                 \
            int row = row0 + r;                                                \
            uint4 val = make_uint4(0, 0, 0, 0);                                \
            if (row < N_NODES)                                                 \
                val = *reinterpret_cast<const uint4*>(A + (size_t)row * lda + (kc) + k8); \
            pa[i] = val;                                                       \
        }                                                                      \
    }
#define LOAD_B(kc)                                                             \
    {                                                                          \
        _Pragma("unroll") for (int i = 0; i < 4; ++i) {                        \
            int u = i * 256 + t, r = u >> 3, k8 = (u & 7) * 8;                 \
            pb[i] = *reinterpret_cast<const uint4*>(BT + (size_t)(cb + r) * K + (kc) + k8); \
        }                                                                      \
    }

    LOAD_A(0);
    LOAD_B(0);

    for (int kc = 0; kc < K; kc += 64) {
#pragma unroll
        for (int i = 0; i < 4; ++i) {
            int u = i * 256 + t, r = u >> 3, k8 = (u & 7) * 8;
            *reinterpret_cast<uint4*>(&sA[r * 72 + k8]) = pa[i];
            *reinterpret_cast<uint4*>(&sB[r * 72 + k8]) = pb[i];
        }
        __syncthreads();
        if (kc + 64 < K) {
            LOAD_A(kc + 64);
            LOAD_B(kc + 64);
        }
#pragma unroll
        for (int ks = 0; ks < 2; ++ks) {
            bf16x8 a0 = *reinterpret_cast<const bf16x8*>(&sA[(w * 32 + ln) * 72 + ks * 32 + q4 * 8]);
            bf16x8 a1 = *reinterpret_cast<const bf16x8*>(&sA[(w * 32 + 16 + ln) * 72 + ks * 32 + q4 * 8]);
#pragma unroll
            for (int nt = 0; nt < 8; ++nt) {
                bf16x8 b = *reinterpret_cast<const bf16x8*>(&sB[(nt * 16 + ln) * 72 + ks * 32 + q4 * 8]);
                acc[0][nt] = __builtin_amdgcn_mfma_f32_16x16x32_bf16(a0, b, acc[0][nt], 0, 0, 0);
                acc[1][nt] = __builtin_amdgcn_mfma_f32_16x16x32_bf16(a1, b, acc[1][nt], 0, 0, 0);
            }
        }
        __syncthreads();
    }
#undef LOAD_A
#undef LOAD_B

    // C frag: row = row0 + w*32 + mt*16 + q4*4 + j ; col = cb + nt*16 + ln
    if (EPI == 0) {
        u16* C = (u16*)Cv;
#pragma unroll
        for (int mt = 0; mt < 2; ++mt)
#pragma unroll
            for (int j = 0; j < 4; ++j) {
                int row = row0 + w * 32 + mt * 16 + q4 * 4 + j;
                if (row < N_NODES) {
#pragma unroll
                    for (int nt = 0; nt < 8; ++nt)
                        C[(size_t)row * ldc + cb + nt * 16 + ln] = f2bf(acc[mt][nt][j]);
                }
            }
    } else if (EPI == 1) {
        u16* C = (u16*)Cv;
        float bs[8], pr[8];
#pragma unroll
        for (int nt = 0; nt < 8; ++nt) {
            int col = cb + nt * 16 + ln;
            bs[nt] = bias[col];
            pr[nt] = prelu[col];
        }
#pragma unroll
        for (int mt = 0; mt < 2; ++mt)
#pragma unroll
            for (int j = 0; j < 4; ++j) {
                int row = row0 + w * 32 + mt * 16 + q4 * 4 + j;
                if (row < N_NODES) {
#pragma unroll
                    for (int nt = 0; nt < 8; ++nt) {
                        float x = acc[mt][nt][j] + bs[nt];
                        x = (x >= 0.f) ? x : pr[nt] * x;
                        C[(size_t)row * ldc + cb + nt * 16 + ln] = f2bf(x);
                    }
                }
            }
    } else {
        // bias + resid(bf16) + row LayerNorm, fp32 out. Block covers all 128 cols.
        float* C = (float*)Cv;
        float bs[8], gv[8], bv[8];
#pragma unroll
        for (int nt = 0; nt < 8; ++nt) {
            int col = cb + nt * 16 + ln;
            bs[nt] = bias[col];
            gv[nt] = g[col];
            bv[nt] = bb[col];
        }
#pragma unroll
        for (int mt = 0; mt < 2; ++mt)
#pragma unroll
            for (int j = 0; j < 4; ++j) {
                int row = row0 + w * 32 + mt * 16 + q4 * 4 + j;
                bool ok = row < N_NODES;
                float vals[8];
                float s = 0.f, ss = 0.f;
#pragma unroll
                for (int nt = 0; nt < 8; ++nt) {
                    float x = acc[mt][nt][j] + bs[nt];
                    if (ok) x += bf2f(resid[(size_t)row * 128 + cb + nt * 16 + ln]);
                    vals[nt] = x;
                    s += x; ss += x * x;
                }
                s += __shfl_xor(s, 8, 16); ss += __shfl_xor(ss, 8, 16);
                s += __shfl_xor(s, 4, 16); ss += __shfl_xor(ss, 4, 16);
                s += __shfl_xor(s, 2, 16); ss += __shfl_xor(ss, 2, 16);
                s += __shfl_xor(s, 1, 16); ss += __shfl_xor(ss, 1, 16);
                float mu = s * (1.f / 128.f);
                float var = ss * (1.f / 128.f) - mu * mu;
                float rs = rsqrtf(var + 1e-5f);
                if (ok) {
#pragma unroll
                    for (int nt = 0; nt < 8; ++nt)
                        C[(size_t)row * 128 + cb + nt * 16 + ln] =
                            (vals[nt] - mu) * rs * gv[nt] + bv[nt];
                }
            }
    }
}

// ---------------- attention: 1 wave per node, 2 dims per lane, unroll-4 ----------------
// qkv packed [n][384] bf16: q 0-127, k 128-255, v 256-383
__global__ __launch_bounds__(256) void k_attn(
    const u16* __restrict__ qkv, const float* __restrict__ feat,
    const int* __restrict__ row_ptr, const int* __restrict__ csr_src,
    const float* __restrict__ g, const float* __restrict__ bb,
    u16* __restrict__ rstb)
{
    const int w = threadIdx.x >> 6;
    const int lane = threadIdx.x & 63;
    const int n = blockIdx.x * 4 + w;
    if (n >= N_NODES) return;
    const int c2 = lane * 2;                 // dims c2, c2+1 (same head: head = lane>>3)
    const float scale = 0.08838834764831845f;  // 1/sqrt(128)

    const u32 qp = *reinterpret_cast<const u32*>(qkv + (size_t)n * 384 + c2);
    const float q0 = blo(qp), q1 = bhi(qp);
    const int e0 = row_ptr[n], e1 = row_ptr[n + 1];

    float m = -INFINITY, l = 0.f, a0 = 0.f, a1 = 0.f;
    int e = e0;
    for (; e + 4 <= e1; e += 4) {
        int s0 = csr_src[e], s1 = csr_src[e + 1], s2 = csr_src[e + 2], s3 = csr_src[e + 3];
        u32 kp0 = *reinterpret_cast<const u32*>(qkv + (size_t)s0 * 384 + 128 + c2);
        u32 kp1 = *reinterpret_cast<const u32*>(qkv + (size_t)s1 * 384 + 128 + c2);
        u32 kp2 = *reinterpret_cast<const u32*>(qkv + (size_t)s2 * 384 + 128 + c2);
        u32 kp3 = *reinterpret_cast<const u32*>(qkv + (size_t)s3 * 384 + 128 + c2);
        u32 vp0 = *reinterpret_cast<const u32*>(qkv + (size_t)s0 * 384 + 256 + c2);
        u32 vp1 = *reinterpret_cast<const u32*>(qkv + (size_t)s1 * 384 + 256 + c2);
        u32 vp2 = *reinterpret_cast<const u32*>(qkv + (size_t)s2 * 384 + 256 + c2);
        u32 vp3 = *reinterpret_cast<const u32*>(qkv + (size_t)s3 * 384 + 256 + c2);
        float p0 = blo(kp0) * q0 + bhi(kp0) * q1;
        float p1 = blo(kp1) * q0 + bhi(kp1) * q1;
        float p2 = blo(kp2) * q0 + bhi(kp2) * q1;
        float p3 = blo(kp3) * q0 + bhi(kp3) * q1;
        p0 += __shfl_xor(p0, 4, 8); p1 += __shfl_xor(p1, 4, 8);
        p2 += __shfl_xor(p2, 4, 8); p3 += __shfl_xor(p3, 4, 8);
        p0 += __shfl_xor(p0, 2, 8); p1 += __shfl_xor(p1, 2, 8);
        p2 += __shfl_xor(p2, 2, 8); p3 += __shfl_xor(p3, 2, 8);
        p0 += __shfl_xor(p0, 1, 8); p1 += __shfl_xor(p1, 1, 8);
        p2 += __shfl_xor(p2, 1, 8); p3 += __shfl_xor(p3, 1, 8);
        float sa = p0 * scale, sb = p1 * scale, sc = p2 * scale, sd = p3 * scale;
        float mn = fmaxf(fmaxf(m, fmaxf(sa, sb)), fmaxf(sc, sd));
        float c = __expf(m - mn);
        float ea = __expf(sa - mn), eb = __expf(sb - mn);
        float ec = __expf(sc - mn), ed = __expf(sd - mn);
        l = l * c + ((ea + eb) + (ec + ed));
        a0 = a0 * c + ea * blo(vp0) + eb * blo(vp1) + ec * blo(vp2) + ed * blo(vp3);
        a1 = a1 * c + ea * bhi(vp0) + eb * bhi(vp1) + ec * bhi(vp2) + ed * bhi(vp3);
        m = mn;
    }
    for (; e < e1; ++e) {
        int s0 = csr_src[e];
        u32 kp0 = *reinterpret_cast<const u32*>(qkv + (size_t)s0 * 384 + 128 + c2);
        u32 vp0 = *reinterpret_cast<const u32*>(qkv + (size_t)s0 * 384 + 256 + c2);
        float p0 = blo(kp0) * q0 + bhi(kp0) * q1;
        p0 += __shfl_xor(p0, 4, 8);
        p0 += __shfl_xor(p0, 2, 8);
        p0 += __shfl_xor(p0, 1, 8);
        float sa = p0 * scale;
        float mn = fmaxf(m, sa);
        float c = __expf(m - mn), ea = __expf(sa - mn);
        l = l * c + ea;
        a0 = a0 * c + ea * blo(vp0);
        a1 = a1 * c + ea * bhi(vp0);
        m = mn;
    }
    float inv = (l > 0.f) ? 1.f / l : 0.f;   // deg-0 node -> 0
    const float2 fr = *reinterpret_cast<const float2*>(feat + (size_t)n * 128 + c2);
    float x0 = a0 * inv + fr.x;
    float x1 = a1 * inv + fr.y;

    // LayerNorm over 128 channels: full-wave shuffle reduce
    float sum = x0 + x1, sq = x0 * x0 + x1 * x1;
#pragma unroll
    for (int off = 32; off >= 1; off >>= 1) {
        sum += __shfl_xor(sum, off, 64);
        sq += __shfl_xor(sq, off, 64);
    }
    float mu = sum * (1.f / 128.f);
    float var = sq * (1.f / 128.f) - mu * mu;
    float rs = rsqrtf(var + 1e-5f);
    float y0 = (x0 - mu) * rs * g[c2] + bb[c2];
    float y1 = (x1 - mu) * rs * g[c2 + 1] + bb[c2 + 1];
    reinterpret_cast<u32*>(rstb)[(size_t)n * 64 + lane] = pack2(y0, y1);
}

extern "C" void kernel_launch(void* const* d_in, const int* in_sizes, int n_in,
                              void* d_out, int out_size, void* d_ws, size_t ws_size,
                              hipStream_t stream)
{
    const float* feat = (const float*)d_in[0];
    const int* src    = (const int*)d_in[1];
    const int* dst    = (const int*)d_in[2];
    const float* Wq   = (const float*)d_in[3];
    const float* Wk   = (const float*)d_in[4];
    const float* Wv   = (const float*)d_in[5];
    const float* ln_g = (const float*)d_in[6];
    const float* ln_b = (const float*)d_in[7];
    const float* W1   = (const float*)d_in[8];
    const float* b1   = (const float*)d_in[9];
    const float* pa   = (const float*)d_in[10];
    const float* W2   = (const float*)d_in[11];
    const float* b2   = (const float*)d_in[12];

    // workspace layout (~106 MB)
    u16* qkv   = (u16*)d_ws;                           // 50000*384
    u16* h     = qkv + (size_t)N_NODES * 384;          // 50000*512 (featb aliases front)
    u16* featb = h;                                    // 50000*128, dead before h written
    u16* rstb  = h + (size_t)N_NODES * 512;            // 50000*128
    u16* WT    = rstb + (size_t)N_NODES * 128;         // 180224
    u16* BqkvT = WT;
    u16* W1T   = WT + 49152;
    u16* W2T   = WT + 114688;
    int* counts  = (int*)(WT + 180224);
    int* fill    = counts + N_NODES;
    int* row_ptr = fill + N_NODES;
    int* csr_src = row_ptr + N_NODES + 1;
    int* bsum    = csr_src + N_EDGES;
    int* boff    = bsum + NB;

    // prep
    k_prepw<<<(180224 + 255) / 256, 256, 0, stream>>>(Wq, Wk, Wv, W1, W2, WT);
    k_prepA<<<(N_NODES * F / 4 + 255) / 256, 256, 0, stream>>>(feat, featb);

    // CSR
    hipMemsetAsync(counts, 0, sizeof(int) * 2 * N_NODES, stream);
    k_hist<<<(N_EDGES + 255) / 256, 256, 0, stream>>>(dst, counts);
    k_bsum<<<NB, 256, 0, stream>>>(counts, bsum);
    k_bscan<<<1, 256, 0, stream>>>(bsum, boff);
    k_bfill<<<NB, 256, 0, stream>>>(counts, boff, row_ptr);
    k_fill<<<(N_EDGES + 255) / 256, 256, 0, stream>>>(src, dst, row_ptr, fill, csr_src);

    const int MBK = (N_NODES + 127) / 128;   // 391

    dim3 gqkv(MBK, 3);
    k_mm<0><<<gqkv, 256, 0, stream>>>(featb, 128, BqkvT, qkv, 384, 128,
                                      nullptr, nullptr, nullptr, nullptr, nullptr);

    k_attn<<<(N_NODES + 3) / 4, 256, 0, stream>>>(qkv, feat, row_ptr, csr_src, ln_g, ln_b, rstb);

    dim3 gf1(MBK, 4);
    k_mm<1><<<gf1, 256, 0, stream>>>(rstb, 128, W1T, h, 512, 128,
                                     b1, pa, nullptr, nullptr, nullptr);

    dim3 gf2(MBK, 1);
    k_mm<2><<<gf2, 256, 0, stream>>>(h, 512, W2T, d_out, 128, 512,
                                     b2, nullptr, rstb, ln_g, ln_b);
}